// Round 12
// baseline (275.932 us; speedup 1.0000x reference)
//
#include <hip/hip_runtime.h>
#include <math.h>

#define N_NODES 50000
#define N_EDGES 800000
#define BATCHES 128
#define DIM 64
#define HID 128
#define NCLS 2
#define EPSV 1e-5f
#define MAXD 64                                   // padded CSR row stride

#define NPART 8
#define PART_SZ ((N_NODES + NPART - 1) / NPART)   // 6250
#define EPB 2048
#define NCHK_E ((N_EDGES + EPB - 1) / EPB)        // 391
#define NCHUNK1 782                               // ceil(N/64)

typedef __attribute__((ext_vector_type(8))) short bf16x8;
typedef __attribute__((ext_vector_type(4))) float f32x4;

// ---- fp32 -> bf16 hi/lo split helpers ----
__device__ __forceinline__ unsigned short f2bf(float f){
  unsigned u = __float_as_uint(f);
  u += 0x7FFFu + ((u >> 16) & 1u);     // RNE
  return (unsigned short)(u >> 16);
}
__device__ __forceinline__ float bf2f(unsigned short h){
  return __uint_as_float(((unsigned)h) << 16);
}
__device__ __forceinline__ void split2(float f, unsigned short& hi, unsigned short& lo){
  hi = f2bf(f);
  lo = f2bf(f - bf2f(hi));
}
__device__ __forceinline__ uint4 pack8(const unsigned short* s){
  uint4 u;
  u.x = (unsigned)s[0] | ((unsigned)s[1] << 16);
  u.y = (unsigned)s[2] | ((unsigned)s[3] << 16);
  u.z = (unsigned)s[4] | ((unsigned)s[5] << 16);
  u.w = (unsigned)s[6] | ((unsigned)s[7] << 16);
  return u;
}

// ---- K1: partitioned fixed-slot scatter -> ushort CSR + cnt ----
__global__ void k_scatter(const int* __restrict__ ei, int* __restrict__ cnt,
                          unsigned short* __restrict__ csr){
  const int p = blockIdx.x & (NPART-1);
  const int c = blockIdx.x >> 3;
  const int lo = p * PART_SZ;
  const int hi = lo + PART_SZ;
  const int e0 = c * EPB;
  const int e1 = (e0 + EPB < N_EDGES) ? e0 + EPB : N_EDGES;
  for (int i = e0 + threadIdx.x; i < e1; i += 256){
    int d = ei[N_EDGES + i];
    if (d >= lo && d < hi){
      int s = ei[i];
      int pos = atomicAdd(&cnt[d], 1);
      csr[(size_t)d*MAXD + pos] = (unsigned short)s;
    }
  }
}

// ---- K2: per-node gather mean (standalone, max wave parallelism). ----
__global__ void k_mean(const float* __restrict__ x,
                       const unsigned short* __restrict__ csr,
                       const int* __restrict__ cnt, float* __restrict__ meanb){
  const int node = (blockIdx.x*256 + threadIdx.x) >> 6;
  const int lane = threadIdx.x & 63;
  const int g = lane >> 4, f = lane & 15;
  const int dg = cnt[node];
  const size_t start = (size_t)node * MAXD;
  float4 acc = make_float4(0.f,0.f,0.f,0.f);
  int e = (lane < dg) ? (int)csr[start + lane] : 0;
  int i = 0;
  for (; i + 16 <= dg; i += 16){
    int s0 = __shfl(e, i +      g, 64);
    int s1 = __shfl(e, i + 4  + g, 64);
    int s2 = __shfl(e, i + 8  + g, 64);
    int s3 = __shfl(e, i + 12 + g, 64);
    float4 v0 = *(const float4*)&x[(size_t)s0*DIM + f*4];
    float4 v1 = *(const float4*)&x[(size_t)s1*DIM + f*4];
    float4 v2 = *(const float4*)&x[(size_t)s2*DIM + f*4];
    float4 v3 = *(const float4*)&x[(size_t)s3*DIM + f*4];
    acc.x += v0.x + v1.x + v2.x + v3.x;
    acc.y += v0.y + v1.y + v2.y + v3.y;
    acc.z += v0.z + v1.z + v2.z + v3.z;
    acc.w += v0.w + v1.w + v2.w + v3.w;
  }
  for (; i < dg; i += 4){
    int idx = i + g;
    int srcl = (idx < dg) ? idx : (dg - 1);   // clamp: wave-uniform shfl
    int s = __shfl(e, srcl, 64);
    if (idx < dg){
      float4 v = *(const float4*)&x[(size_t)s*DIM + f*4];
      acc.x += v.x; acc.y += v.y; acc.z += v.z; acc.w += v.w;
    }
  }
  acc.x += __shfl_xor(acc.x, 16, 64); acc.x += __shfl_xor(acc.x, 32, 64);
  acc.y += __shfl_xor(acc.y, 16, 64); acc.y += __shfl_xor(acc.y, 32, 64);
  acc.z += __shfl_xor(acc.z, 16, 64); acc.z += __shfl_xor(acc.z, 32, 64);
  acc.w += __shfl_xor(acc.w, 16, 64); acc.w += __shfl_xor(acc.w, 32, 64);
  if (g == 0){
    float inv = 1.f / fmaxf((float)dg, 1.f);
    float4 r = make_float4(acc.x*inv, acc.y*inv, acc.z*inv, acc.w*inv);
    *(float4*)&meanb[(size_t)node*DIM + f*4] = r;
  }
}

// =====================================================================
// K3 (MFMA): hpre = [mean|x] @ [Wl;Wr] + bl ; stats partials per block.
// (R10 structure: LDS-staged A — measured fastest.)
// =====================================================================
__global__ void __launch_bounds__(256) k_lin1(
    const float* __restrict__ meanb, const float* __restrict__ x,
    const float* __restrict__ Wl, const float* __restrict__ bl,
    const float* __restrict__ Wr, float* __restrict__ hbuf,
    float* __restrict__ pstat){
  __shared__ __align__(16) short sB[2][64][136];   // Bt[n][k] k<64:Wl k>=64:Wr
  __shared__ __align__(16) short sA[2][64][72];    // A[node][k] (one half)
  const int tid  = threadIdx.x;
  const int lane = tid & 63, w = tid >> 6;
  const int jc   = lane & 15;
  const int mrow = 16*w + jc;
  const int koff = (lane >> 4) * 8;
  const int r0   = 16*w + (lane >> 4)*4;
  const int base = blockIdx.x * 64;

  // ---- stage weights: Bt[j][k] ----
  {
    const int k0 = 32 * w;
    #pragma unroll
    for (int kc = 0; kc < 4; ++kc){
      unsigned short h[8], l[8];
      #pragma unroll
      for (int i = 0; i < 8; ++i){
        int k = k0 + 8*kc + i;
        float v = (k < 64) ? Wl[k*DIM + lane] : Wr[(k-64)*DIM + lane];
        split2(v, h[i], l[i]);
      }
      *(uint4*)&sB[0][lane][k0 + 8*kc] = pack8(h);
      *(uint4*)&sB[1][lane][k0 + 8*kc] = pack8(l);
    }
  }

  float blv[4];
  #pragma unroll
  for (int nt = 0; nt < 4; ++nt) blv[nt] = bl[nt*16 + jc];

  f32x4 acc[4] = {};
  #pragma unroll
  for (int half = 0; half < 2; ++half){
    const float* __restrict__ src = half ? x : meanb;
    __syncthreads();
    {
      const int row = tid >> 2;
      const int kq  = (tid & 3) * 16;
      const int node = base + row;
      #pragma unroll
      for (int cc = 0; cc < 4; ++cc){
        float4 v = make_float4(0.f,0.f,0.f,0.f);
        if (node < N_NODES) v = *(const float4*)&src[(size_t)node*DIM + kq + 4*cc];
        unsigned short h[4], l[4];
        split2(v.x,h[0],l[0]); split2(v.y,h[1],l[1]);
        split2(v.z,h[2],l[2]); split2(v.w,h[3],l[3]);
        uint2 ph, pl;
        ph.x = (unsigned)h[0] | ((unsigned)h[1]<<16);
        ph.y = (unsigned)h[2] | ((unsigned)h[3]<<16);
        pl.x = (unsigned)l[0] | ((unsigned)l[1]<<16);
        pl.y = (unsigned)l[2] | ((unsigned)l[3]<<16);
        *(uint2*)&sA[0][row][kq + 4*cc] = ph;
        *(uint2*)&sA[1][row][kq + 4*cc] = pl;
      }
    }
    __syncthreads();
    #pragma unroll
    for (int kt2 = 0; kt2 < 2; ++kt2){
      const int ka = kt2*32 + koff;        // A k (0..63)
      const int kb = half*64 + ka;         // B k (0..127)
      bf16x8 ah = *(const bf16x8*)&sA[0][mrow][ka];
      bf16x8 al = *(const bf16x8*)&sA[1][mrow][ka];
      #pragma unroll
      for (int nt = 0; nt < 4; ++nt){
        const int nr = nt*16 + jc;
        bf16x8 bh = *(const bf16x8*)&sB[0][nr][kb];
        bf16x8 bo = *(const bf16x8*)&sB[1][nr][kb];
        acc[nt] = __builtin_amdgcn_mfma_f32_16x16x32_bf16(ah, bh, acc[nt], 0,0,0);
        acc[nt] = __builtin_amdgcn_mfma_f32_16x16x32_bf16(al, bh, acc[nt], 0,0,0);
        acc[nt] = __builtin_amdgcn_mfma_f32_16x16x32_bf16(ah, bo, acc[nt], 0,0,0);
      }
    }
  }

  // epilogue: bias, global write, stats partials
  float s1[4] = {0.f,0.f,0.f,0.f}, s2[4] = {0.f,0.f,0.f,0.f};
  #pragma unroll
  for (int nt = 0; nt < 4; ++nt){
    const int col = nt*16 + jc;
    #pragma unroll
    for (int r = 0; r < 4; ++r){
      const int node = base + r0 + r;
      float v = acc[nt][r] + blv[nt];
      if (node < N_NODES){
        hbuf[(size_t)node*DIM + col] = v;
        s1[nt] += v; s2[nt] += v*v;
      }
    }
  }

  __syncthreads();
  float* sred = (float*)sA;      // 512 floats
  #pragma unroll
  for (int nt = 0; nt < 4; ++nt){
    float a = s1[nt], b = s2[nt];
    a += __shfl_xor(a, 16, 64); a += __shfl_xor(a, 32, 64);
    b += __shfl_xor(b, 16, 64); b += __shfl_xor(b, 32, 64);
    if ((lane >> 4) == 0){
      sred[0*256 + w*64 + nt*16 + jc] = a;
      sred[1*256 + w*64 + nt*16 + jc] = b;
    }
  }
  __syncthreads();
  if (tid < 64){
    float a = sred[tid] + sred[64+tid] + sred[128+tid] + sred[192+tid];
    float b = sred[256+tid] + sred[320+tid] + sred[384+tid] + sred[448+tid];
    pstat[(size_t)blockIdx.x*128 + tid]      = a;
    pstat[(size_t)blockIdx.x*128 + 64 + tid] = b;
  }
}

// ---- K4: parallel reduce of per-block partials -> mu / inv-std ----
__global__ void __launch_bounds__(256) k_stats(
    const float* __restrict__ pstat, float* __restrict__ muinv){
  __shared__ float r1[256], r2[256];
  const int j = blockIdx.x;            // 0..63
  const int t = threadIdx.x;
  float s1 = 0.f, s2 = 0.f;
  for (int c = t; c < NCHUNK1; c += 256){
    s1 += pstat[(size_t)c*128 + j];
    s2 += pstat[(size_t)c*128 + 64 + j];
  }
  r1[t] = s1; r2[t] = s2;
  __syncthreads();
  for (int st = 128; st > 0; st >>= 1){
    if (t < st){ r1[t] += r1[t+st]; r2[t] += r2[t+st]; }
    __syncthreads();
  }
  if (t == 0){
    float mu = r1[0] / (float)N_NODES;
    float var = r2[0] / (float)N_NODES - mu*mu;
    muinv[j] = mu;
    muinv[DIM+j] = 1.0f / sqrtf(var + EPSV);
  }
}

// helper: stage 64x64 weight transposed as bf16 hi/lo into [64][72] rows
__device__ __forceinline__ void stage_w64(short* sWh, short* sWl_,
                                          const float* __restrict__ W,
                                          int w, int lane){
  const int k0 = 16 * w;
  #pragma unroll
  for (int kc = 0; kc < 2; ++kc){
    unsigned short h[8], l[8];
    #pragma unroll
    for (int i = 0; i < 8; ++i){
      int k = k0 + 8*kc + i;
      split2(W[k*DIM + lane], h[i], l[i]);
    }
    *(uint4*)&sWh[lane*72 + k0 + 8*kc] = pack8(h);
    *(uint4*)&sWl_[lane*72 + k0 + 8*kc] = pack8(l);
  }
}

// =====================================================================
// K5 (MFMA, fused pooling + last-block head): h2 = BN(hpre)+x@Wres+bres
// (registers/LDS only); gate -> e=exp(g) unshifted; run-aware pooled/zbuf
// atomics; LAST block (donecnt) computes the head MLP and writes out.
// =====================================================================
__global__ void __launch_bounds__(256) k_lin2(
    const float* __restrict__ x, const float* __restrict__ hbuf,
    const float* __restrict__ Wres, const float* __restrict__ bres,
    const float* __restrict__ gamma, const float* __restrict__ beta,
    const float* __restrict__ muinv,
    const float* __restrict__ gW1, const float* __restrict__ gb1,
    const float* __restrict__ gW2, const float* __restrict__ gb2,
    const int* __restrict__ batch,
    float* __restrict__ zbuf, float* __restrict__ pooled,
    const float* __restrict__ Wp1, const float* __restrict__ bp1,
    const float* __restrict__ Wp2, const float* __restrict__ bp2,
    float* __restrict__ outp, unsigned* __restrict__ donecnt){
  __shared__ __align__(16) short sW[2][64][72];
  __shared__ __align__(16) short sA[2][64][72];
  __shared__ int sb[64];
  __shared__ unsigned long long runmask;
  __shared__ unsigned sdone;
  const int tid  = threadIdx.x;
  const int lane = tid & 63, w = tid >> 6;
  const int jc   = lane & 15;
  const int g16  = w*4 + (lane >> 4);     // group id 0..15, owns rows 4*g16..+3
  const int mrow = 16*w + jc;
  const int koff = (lane >> 4) * 8;
  const int r0   = 16*w + (lane >> 4)*4;  // == 4*g16
  const int base = blockIdx.x * 64;

  float muv[4], invv[4], gav[4], bev[4], brv[4], g1v[4], w2v[4];
  #pragma unroll
  for (int nt = 0; nt < 4; ++nt){
    const int col = nt*16 + jc;
    muv[nt] = muinv[col];  invv[nt] = muinv[DIM+col];
    gav[nt] = gamma[col];  bev[nt]  = beta[col];
    brv[nt] = bres[col];   g1v[nt]  = gb1[col];
    w2v[nt] = gW2[col];
  }
  const float gb2v = gb2[0];

  // stage x into sA ; stage batch ids
  {
    const int row = tid >> 2;
    const int kq  = (tid & 3) * 16;
    const int node = base + row;
    #pragma unroll
    for (int cc = 0; cc < 4; ++cc){
      float4 v = make_float4(0.f,0.f,0.f,0.f);
      if (node < N_NODES) v = *(const float4*)&x[(size_t)node*DIM + kq + 4*cc];
      unsigned short h[4], l[4];
      split2(v.x,h[0],l[0]); split2(v.y,h[1],l[1]);
      split2(v.z,h[2],l[2]); split2(v.w,h[3],l[3]);
      uint2 ph, pl;
      ph.x = (unsigned)h[0] | ((unsigned)h[1]<<16);
      ph.y = (unsigned)h[2] | ((unsigned)h[3]<<16);
      pl.x = (unsigned)l[0] | ((unsigned)l[1]<<16);
      pl.y = (unsigned)l[2] | ((unsigned)l[3]<<16);
      *(uint2*)&sA[0][row][kq + 4*cc] = ph;
      *(uint2*)&sA[1][row][kq + 4*cc] = pl;
    }
  }
  if (tid < 64){
    int nn = base + tid;
    sb[tid] = batch[(nn < N_NODES) ? nn : (N_NODES-1)];
  }
  stage_w64(&sW[0][0][0], &sW[1][0][0], Wres, w, lane);
  __syncthreads();

  if (w == 0){
    bool fl = (lane > 0) && (sb[lane] != sb[lane-1]);
    unsigned long long mm = __ballot(fl);
    if (lane == 0) runmask = mm;
  }

  // GEMM1: acc = x @ Wres
  f32x4 acc[4] = {};
  #pragma unroll
  for (int kt2 = 0; kt2 < 2; ++kt2){
    const int ka = kt2*32 + koff;
    bf16x8 ah = *(const bf16x8*)&sA[0][mrow][ka];
    bf16x8 al = *(const bf16x8*)&sA[1][mrow][ka];
    #pragma unroll
    for (int nt = 0; nt < 4; ++nt){
      const int nr = nt*16 + jc;
      bf16x8 bh = *(const bf16x8*)&sW[0][nr][ka];
      bf16x8 bo = *(const bf16x8*)&sW[1][nr][ka];
      acc[nt] = __builtin_amdgcn_mfma_f32_16x16x32_bf16(ah, bh, acc[nt], 0,0,0);
      acc[nt] = __builtin_amdgcn_mfma_f32_16x16x32_bf16(al, bh, acc[nt], 0,0,0);
      acc[nt] = __builtin_amdgcn_mfma_f32_16x16x32_bf16(ah, bo, acc[nt], 0,0,0);
    }
  }

  // epilogue1: h2 = BN(hpre)+bres+acc ; keep in vk ; convert into sA
  float vk[4][4];
  #pragma unroll
  for (int nt = 0; nt < 4; ++nt){
    const int col = nt*16 + jc;
    #pragma unroll
    for (int r = 0; r < 4; ++r){
      const int node = base + r0 + r;
      float hp = 0.f;
      if (node < N_NODES) hp = hbuf[(size_t)node*DIM + col];
      float v = (hp - muv[nt])*invv[nt]*gav[nt] + bev[nt] + brv[nt] + acc[nt][r];
      vk[nt][r] = v;
      unsigned short hh, ll;
      split2(v, hh, ll);
      sA[0][r0 + r][col] = (short)hh;    // own-wave rows: no sync needed
      sA[1][r0 + r][col] = (short)ll;
    }
  }
  __syncthreads();
  stage_w64(&sW[0][0][0], &sW[1][0][0], gW1, w, lane);
  __syncthreads();

  // GEMM2: gp = h2 @ gW1
  f32x4 acc2[4] = {};
  #pragma unroll
  for (int kt2 = 0; kt2 < 2; ++kt2){
    const int ka = kt2*32 + koff;
    bf16x8 ah = *(const bf16x8*)&sA[0][mrow][ka];
    bf16x8 al = *(const bf16x8*)&sA[1][mrow][ka];
    #pragma unroll
    for (int nt = 0; nt < 4; ++nt){
      const int nr = nt*16 + jc;
      bf16x8 bh = *(const bf16x8*)&sW[0][nr][ka];
      bf16x8 bo = *(const bf16x8*)&sW[1][nr][ka];
      acc2[nt] = __builtin_amdgcn_mfma_f32_16x16x32_bf16(ah, bh, acc2[nt], 0,0,0);
      acc2[nt] = __builtin_amdgcn_mfma_f32_16x16x32_bf16(al, bh, acc2[nt], 0,0,0);
      acc2[nt] = __builtin_amdgcn_mfma_f32_16x16x32_bf16(ah, bo, acc2[nt], 0,0,0);
    }
  }

  // epilogue2: gate scalar per node -> e weights (all 16 lanes of group hold it)
  float p[4] = {0.f,0.f,0.f,0.f};
  #pragma unroll
  for (int nt = 0; nt < 4; ++nt){
    #pragma unroll
    for (int r = 0; r < 4; ++r)
      p[r] += fmaxf(acc2[nt][r] + g1v[nt], 0.f) * w2v[nt];
  }
  float ev[4];
  #pragma unroll
  for (int r = 0; r < 4; ++r){
    float t = p[r];
    t += __shfl_xor(t, 1, 64); t += __shfl_xor(t, 2, 64);
    t += __shfl_xor(t, 4, 64); t += __shfl_xor(t, 8, 64);
    const int node = base + r0 + r;
    ev[r] = (node < N_NODES) ? expf(t + gb2v) : 0.f;
  }

  // ---- fused pooling: run-aware block reduce -> global atomics ----
  float* sredp = (float*)&sW[0][0][0];   // alias: 16*64 + 16 floats <= sW size
  float* szl   = sredp + 16*64;
  __syncthreads();                       // sW reads (GEMM2) complete
  const unsigned long long m = runmask;
  int rstart = 0;
  while (rstart < 64){
    const int bseg = sb[rstart];         // uniform
    unsigned long long rest = (rstart >= 63) ? 0ull : (m >> (rstart+1));
    const int rend = rest ? (rstart + 1 + __builtin_ctzll(rest)) : 64;
    float pacc[4] = {0.f,0.f,0.f,0.f};
    float zacc = 0.f;
    #pragma unroll
    for (int r = 0; r < 4; ++r){
      const int ln = 4*g16 + r;
      if (ln >= rstart && ln < rend){
        #pragma unroll
        for (int nt = 0; nt < 4; ++nt) pacc[nt] += ev[r]*vk[nt][r];
        zacc += ev[r];
      }
    }
    #pragma unroll
    for (int nt = 0; nt < 4; ++nt) sredp[g16*64 + nt*16 + jc] = pacc[nt];
    if ((lane & 15) == 0) szl[g16] = zacc;
    __syncthreads();
    if (tid < 64){
      float s = 0.f;
      #pragma unroll 4
      for (int g2 = 0; g2 < 16; ++g2) s += sredp[g2*64 + tid];
      atomicAdd(&pooled[bseg*DIM + tid], s);
    }
    if (tid == 64){
      float sz2 = 0.f;
      for (int g2 = 0; g2 < 16; ++g2) sz2 += szl[g2];
      atomicAdd(&zbuf[bseg], sz2);
    }
    __syncthreads();
    rstart = rend;
  }

  // ---- last-block detection: the 782nd arriver computes the head ----
  __threadfence();
  __syncthreads();
  if (tid == 0) sdone = atomicAdd(donecnt, 1u);
  __syncthreads();
  if (sdone != (unsigned)(gridDim.x - 1)) return;

  // head: pooled/z -> relu(@Wp1+bp1)@Wp2+bp2 -> out (all pooling visible;
  // volatile loads read through to L2, bypassing this CU's L1)
  volatile const float* vp = pooled;
  volatile const float* vz = zbuf;
  float* sp  = (float*)&sA[0][0][0];     // 64 rows x 64 = 16 KB per phase
  float* szb = (float*)&sW[0][0][0];     // 64 floats per phase
  for (int phase = 0; phase < 2; ++phase){
    for (int i = tid; i < 64*DIM; i += 256) sp[i] = vp[phase*64*DIM + i];
    if (tid < 64) szb[tid] = vz[phase*64 + tid];
    __syncthreads();
    for (int b2 = w; b2 < 64; b2 += 4){        // wave w handles rows b2 = w,w+4,...
      const int b = phase*64 + b2;
      const float inv = 1.f / fmaxf(szb[b2], 1e-16f);
      float a0 = bp1[lane], a1 = bp1[lane + 64];
      #pragma unroll
      for (int d2 = 0; d2 < DIM; ++d2){
        float pv = sp[b2*DIM + d2] * inv;      // LDS broadcast
        a0 = fmaf(pv, Wp1[d2*HID + lane],      a0);
        a1 = fmaf(pv, Wp1[d2*HID + lane + 64], a1);
      }
      a0 = fmaxf(a0, 0.f); a1 = fmaxf(a1, 0.f);
      float o0 = a0*Wp2[lane*NCLS+0] + a1*Wp2[(lane+64)*NCLS+0];
      float o1 = a0*Wp2[lane*NCLS+1] + a1*Wp2[(lane+64)*NCLS+1];
      #pragma unroll
      for (int o = 32; o > 0; o >>= 1){
        o0 += __shfl_down(o0, o, 64);
        o1 += __shfl_down(o1, o, 64);
      }
      if (lane == 0){ outp[b*NCLS+0] = o0; outp[b*NCLS+1] = o1; }
    }
    __syncthreads();
  }
}

extern "C" void kernel_launch(void* const* d_in, const int* in_sizes, int n_in,
                              void* d_out, int out_size, void* d_ws, size_t ws_size,
                              hipStream_t stream){
  const float* x     = (const float*)d_in[0];
  const int*   ei    = (const int*)d_in[1];
  const int*   batch = (const int*)d_in[2];
  const float* Wl    = (const float*)d_in[3];
  const float* bl    = (const float*)d_in[4];
  const float* Wr    = (const float*)d_in[5];
  const float* Wres  = (const float*)d_in[6];
  const float* bres  = (const float*)d_in[7];
  const float* gamma = (const float*)d_in[8];
  const float* beta  = (const float*)d_in[9];
  const float* gW1   = (const float*)d_in[10];
  const float* gb1   = (const float*)d_in[11];
  const float* gW2   = (const float*)d_in[12];
  const float* gb2   = (const float*)d_in[13];
  const float* Wp1   = (const float*)d_in[14];
  const float* bp1   = (const float*)d_in[15];
  const float* Wp2   = (const float*)d_in[16];
  const float* bp2   = (const float*)d_in[17];
  float* outp = (float*)d_out;

  // ---- workspace carve (zero-init region first, contiguous) ----
  int*      cnt   = (int*)d_ws;                          // N      (zeroed)
  float*    zbuf  = (float*)(cnt + N_NODES);             // B      (zeroed)
  float*    pooled= zbuf + BATCHES;                      // B*D    (zeroed)
  unsigned* done  = (unsigned*)(pooled + (size_t)BATCHES*DIM); // 4   (zeroed)
  float*    pstat = (float*)(done + 4);                  // NCHUNK1*128
  float*    muinv = pstat + (size_t)NCHUNK1*128;         // 128
  float*    meanb = muinv + 2*DIM;                       // N*D
  float*    hbuf  = meanb + (size_t)N_NODES*DIM;         // N*D
  unsigned short* csr = (unsigned short*)(hbuf + (size_t)N_NODES*DIM); // N*MAXD u16

  const size_t zcount = (size_t)N_NODES + BATCHES + (size_t)BATCHES*DIM + 4;
  hipMemsetAsync(d_ws, 0, zcount*sizeof(int), stream);

  k_scatter<<<NPART*NCHK_E, 256, 0, stream>>>(ei, cnt, csr);
  k_mean   <<<N_NODES/4, 256, 0, stream>>>(x, csr, cnt, meanb);
  k_lin1   <<<NCHUNK1, 256, 0, stream>>>(meanb, x, Wl, bl, Wr, hbuf, pstat);
  k_stats  <<<64, 256, 0, stream>>>(pstat, muinv);
  k_lin2   <<<NCHUNK1, 256, 0, stream>>>(x, hbuf, Wres, bres, gamma, beta, muinv,
                                         gW1, gb1, gW2, gb2, batch, zbuf, pooled,
                                         Wp1, bp1, Wp2, bp2, outp, done);
}

// Round 13
// 198.712 us; speedup vs baseline: 1.3886x; 1.3886x over previous
//
#include <hip/hip_runtime.h>
#include <math.h>

#define N_NODES 50000
#define N_EDGES 800000
#define BATCHES 128
#define DIM 64
#define HID 128
#define NCLS 2
#define EPSV 1e-5f
#define MAXD 64                                   // padded CSR row stride

#define NPART 8
#define PART_SZ ((N_NODES + NPART - 1) / NPART)   // 6250
#define EPB 2048
#define NCHK_E ((N_EDGES + EPB - 1) / EPB)        // 391
#define NCHUNK1 782                               // ceil(N/64)

typedef __attribute__((ext_vector_type(8))) short bf16x8;
typedef __attribute__((ext_vector_type(4))) float f32x4;

// ---- fp32 -> bf16 hi/lo split helpers ----
__device__ __forceinline__ unsigned short f2bf(float f){
  unsigned u = __float_as_uint(f);
  u += 0x7FFFu + ((u >> 16) & 1u);     // RNE
  return (unsigned short)(u >> 16);
}
__device__ __forceinline__ float bf2f(unsigned short h){
  return __uint_as_float(((unsigned)h) << 16);
}
__device__ __forceinline__ void split2(float f, unsigned short& hi, unsigned short& lo){
  hi = f2bf(f);
  lo = f2bf(f - bf2f(hi));
}
__device__ __forceinline__ uint4 pack8(const unsigned short* s){
  uint4 u;
  u.x = (unsigned)s[0] | ((unsigned)s[1] << 16);
  u.y = (unsigned)s[2] | ((unsigned)s[3] << 16);
  u.z = (unsigned)s[4] | ((unsigned)s[5] << 16);
  u.w = (unsigned)s[6] | ((unsigned)s[7] << 16);
  return u;
}

// ---- K1: partitioned fixed-slot scatter -> ushort CSR + cnt ----
__global__ void k_scatter(const int* __restrict__ ei, int* __restrict__ cnt,
                          unsigned short* __restrict__ csr){
  const int p = blockIdx.x & (NPART-1);
  const int c = blockIdx.x >> 3;
  const int lo = p * PART_SZ;
  const int hi = lo + PART_SZ;
  const int e0 = c * EPB;
  const int e1 = (e0 + EPB < N_EDGES) ? e0 + EPB : N_EDGES;
  for (int i = e0 + threadIdx.x; i < e1; i += 256){
    int d = ei[N_EDGES + i];
    if (d >= lo && d < hi){
      int s = ei[i];
      int pos = atomicAdd(&cnt[d], 1);
      csr[(size_t)d*MAXD + pos] = (unsigned short)s;
    }
  }
}

// ---- K2: per-node gather mean (standalone, max wave parallelism). ----
__global__ void k_mean(const float* __restrict__ x,
                       const unsigned short* __restrict__ csr,
                       const int* __restrict__ cnt, float* __restrict__ meanb){
  const int node = (blockIdx.x*256 + threadIdx.x) >> 6;
  const int lane = threadIdx.x & 63;
  const int g = lane >> 4, f = lane & 15;
  const int dg = cnt[node];
  const size_t start = (size_t)node * MAXD;
  float4 acc = make_float4(0.f,0.f,0.f,0.f);
  int e = (lane < dg) ? (int)csr[start + lane] : 0;
  int i = 0;
  for (; i + 16 <= dg; i += 16){
    int s0 = __shfl(e, i +      g, 64);
    int s1 = __shfl(e, i + 4  + g, 64);
    int s2 = __shfl(e, i + 8  + g, 64);
    int s3 = __shfl(e, i + 12 + g, 64);
    float4 v0 = *(const float4*)&x[(size_t)s0*DIM + f*4];
    float4 v1 = *(const float4*)&x[(size_t)s1*DIM + f*4];
    float4 v2 = *(const float4*)&x[(size_t)s2*DIM + f*4];
    float4 v3 = *(const float4*)&x[(size_t)s3*DIM + f*4];
    acc.x += v0.x + v1.x + v2.x + v3.x;
    acc.y += v0.y + v1.y + v2.y + v3.y;
    acc.z += v0.z + v1.z + v2.z + v3.z;
    acc.w += v0.w + v1.w + v2.w + v3.w;
  }
  for (; i < dg; i += 4){
    int idx = i + g;
    int srcl = (idx < dg) ? idx : (dg - 1);   // clamp: wave-uniform shfl
    int s = __shfl(e, srcl, 64);
    if (idx < dg){
      float4 v = *(const float4*)&x[(size_t)s*DIM + f*4];
      acc.x += v.x; acc.y += v.y; acc.z += v.z; acc.w += v.w;
    }
  }
  acc.x += __shfl_xor(acc.x, 16, 64); acc.x += __shfl_xor(acc.x, 32, 64);
  acc.y += __shfl_xor(acc.y, 16, 64); acc.y += __shfl_xor(acc.y, 32, 64);
  acc.z += __shfl_xor(acc.z, 16, 64); acc.z += __shfl_xor(acc.z, 32, 64);
  acc.w += __shfl_xor(acc.w, 16, 64); acc.w += __shfl_xor(acc.w, 32, 64);
  if (g == 0){
    float inv = 1.f / fmaxf((float)dg, 1.f);
    float4 r = make_float4(acc.x*inv, acc.y*inv, acc.z*inv, acc.w*inv);
    *(float4*)&meanb[(size_t)node*DIM + f*4] = r;
  }
}

// =====================================================================
// K3 (MFMA): hpre = [mean|x] @ [Wl;Wr] + bl ; stats partials per block.
// =====================================================================
__global__ void __launch_bounds__(256) k_lin1(
    const float* __restrict__ meanb, const float* __restrict__ x,
    const float* __restrict__ Wl, const float* __restrict__ bl,
    const float* __restrict__ Wr, float* __restrict__ hbuf,
    float* __restrict__ pstat){
  __shared__ __align__(16) short sB[2][64][136];   // Bt[n][k] k<64:Wl k>=64:Wr
  __shared__ __align__(16) short sA[2][64][72];    // A[node][k] (one half)
  const int tid  = threadIdx.x;
  const int lane = tid & 63, w = tid >> 6;
  const int jc   = lane & 15;
  const int mrow = 16*w + jc;
  const int koff = (lane >> 4) * 8;
  const int r0   = 16*w + (lane >> 4)*4;
  const int base = blockIdx.x * 64;

  // ---- stage weights: Bt[j][k] ----
  {
    const int k0 = 32 * w;
    #pragma unroll
    for (int kc = 0; kc < 4; ++kc){
      unsigned short h[8], l[8];
      #pragma unroll
      for (int i = 0; i < 8; ++i){
        int k = k0 + 8*kc + i;
        float v = (k < 64) ? Wl[k*DIM + lane] : Wr[(k-64)*DIM + lane];
        split2(v, h[i], l[i]);
      }
      *(uint4*)&sB[0][lane][k0 + 8*kc] = pack8(h);
      *(uint4*)&sB[1][lane][k0 + 8*kc] = pack8(l);
    }
  }

  float blv[4];
  #pragma unroll
  for (int nt = 0; nt < 4; ++nt) blv[nt] = bl[nt*16 + jc];

  f32x4 acc[4] = {};
  #pragma unroll
  for (int half = 0; half < 2; ++half){
    const float* __restrict__ src = half ? x : meanb;
    __syncthreads();
    {
      const int row = tid >> 2;
      const int kq  = (tid & 3) * 16;
      const int node = base + row;
      #pragma unroll
      for (int cc = 0; cc < 4; ++cc){
        float4 v = make_float4(0.f,0.f,0.f,0.f);
        if (node < N_NODES) v = *(const float4*)&src[(size_t)node*DIM + kq + 4*cc];
        unsigned short h[4], l[4];
        split2(v.x,h[0],l[0]); split2(v.y,h[1],l[1]);
        split2(v.z,h[2],l[2]); split2(v.w,h[3],l[3]);
        uint2 ph, pl;
        ph.x = (unsigned)h[0] | ((unsigned)h[1]<<16);
        ph.y = (unsigned)h[2] | ((unsigned)h[3]<<16);
        pl.x = (unsigned)l[0] | ((unsigned)l[1]<<16);
        pl.y = (unsigned)l[2] | ((unsigned)l[3]<<16);
        *(uint2*)&sA[0][row][kq + 4*cc] = ph;
        *(uint2*)&sA[1][row][kq + 4*cc] = pl;
      }
    }
    __syncthreads();
    #pragma unroll
    for (int kt2 = 0; kt2 < 2; ++kt2){
      const int ka = kt2*32 + koff;        // A k (0..63)
      const int kb = half*64 + ka;         // B k (0..127)
      bf16x8 ah = *(const bf16x8*)&sA[0][mrow][ka];
      bf16x8 al = *(const bf16x8*)&sA[1][mrow][ka];
      #pragma unroll
      for (int nt = 0; nt < 4; ++nt){
        const int nr = nt*16 + jc;
        bf16x8 bh = *(const bf16x8*)&sB[0][nr][kb];
        bf16x8 bo = *(const bf16x8*)&sB[1][nr][kb];
        acc[nt] = __builtin_amdgcn_mfma_f32_16x16x32_bf16(ah, bh, acc[nt], 0,0,0);
        acc[nt] = __builtin_amdgcn_mfma_f32_16x16x32_bf16(al, bh, acc[nt], 0,0,0);
        acc[nt] = __builtin_amdgcn_mfma_f32_16x16x32_bf16(ah, bo, acc[nt], 0,0,0);
      }
    }
  }

  // epilogue: bias, global write, stats partials
  float s1[4] = {0.f,0.f,0.f,0.f}, s2[4] = {0.f,0.f,0.f,0.f};
  #pragma unroll
  for (int nt = 0; nt < 4; ++nt){
    const int col = nt*16 + jc;
    #pragma unroll
    for (int r = 0; r < 4; ++r){
      const int node = base + r0 + r;
      float v = acc[nt][r] + blv[nt];
      if (node < N_NODES){
        hbuf[(size_t)node*DIM + col] = v;
        s1[nt] += v; s2[nt] += v*v;
      }
    }
  }

  __syncthreads();
  float* sred = (float*)sA;      // 512 floats
  #pragma unroll
  for (int nt = 0; nt < 4; ++nt){
    float a = s1[nt], b = s2[nt];
    a += __shfl_xor(a, 16, 64); a += __shfl_xor(a, 32, 64);
    b += __shfl_xor(b, 16, 64); b += __shfl_xor(b, 32, 64);
    if ((lane >> 4) == 0){
      sred[0*256 + w*64 + nt*16 + jc] = a;
      sred[1*256 + w*64 + nt*16 + jc] = b;
    }
  }
  __syncthreads();
  if (tid < 64){
    float a = sred[tid] + sred[64+tid] + sred[128+tid] + sred[192+tid];
    float b = sred[256+tid] + sred[320+tid] + sred[384+tid] + sred[448+tid];
    pstat[(size_t)blockIdx.x*128 + tid]      = a;
    pstat[(size_t)blockIdx.x*128 + 64 + tid] = b;
  }
}

// ---- K4: parallel reduce of per-block partials -> mu / inv-std ----
__global__ void __launch_bounds__(256) k_stats(
    const float* __restrict__ pstat, float* __restrict__ muinv){
  __shared__ float r1[256], r2[256];
  const int j = blockIdx.x;            // 0..63
  const int t = threadIdx.x;
  float s1 = 0.f, s2 = 0.f;
  for (int c = t; c < NCHUNK1; c += 256){
    s1 += pstat[(size_t)c*128 + j];
    s2 += pstat[(size_t)c*128 + 64 + j];
  }
  r1[t] = s1; r2[t] = s2;
  __syncthreads();
  for (int st = 128; st > 0; st >>= 1){
    if (t < st){ r1[t] += r1[t+st]; r2[t] += r2[t+st]; }
    __syncthreads();
  }
  if (t == 0){
    float mu = r1[0] / (float)N_NODES;
    float var = r2[0] / (float)N_NODES - mu*mu;
    muinv[j] = mu;
    muinv[DIM+j] = 1.0f / sqrtf(var + EPSV);
  }
}

// helper: stage 64x64 weight transposed as bf16 hi/lo into [64][72] rows
__device__ __forceinline__ void stage_w64(short* sWh, short* sWl_,
                                          const float* __restrict__ W,
                                          int w, int lane){
  const int k0 = 16 * w;
  #pragma unroll
  for (int kc = 0; kc < 2; ++kc){
    unsigned short h[8], l[8];
    #pragma unroll
    for (int i = 0; i < 8; ++i){
      int k = k0 + 8*kc + i;
      split2(W[k*DIM + lane], h[i], l[i]);
    }
    *(uint4*)&sWh[lane*72 + k0 + 8*kc] = pack8(h);
    *(uint4*)&sWl_[lane*72 + k0 + 8*kc] = pack8(l);
  }
}

// =====================================================================
// K5 (MFMA, fused pooling): h2 = BN(hpre)+x@Wres+bres (registers/LDS only);
// gate = relu(h2@gW1+gb1)@gW2+gb2 ; e=exp(gate) unshifted; run-aware block
// reduction of (e·h2, e) -> atomicAdd into pooled/zbuf. No h2/gbuf globals.
// =====================================================================
__global__ void __launch_bounds__(256) k_lin2(
    const float* __restrict__ x, const float* __restrict__ hbuf,
    const float* __restrict__ Wres, const float* __restrict__ bres,
    const float* __restrict__ gamma, const float* __restrict__ beta,
    const float* __restrict__ muinv,
    const float* __restrict__ gW1, const float* __restrict__ gb1,
    const float* __restrict__ gW2, const float* __restrict__ gb2,
    const int* __restrict__ batch,
    float* __restrict__ zbuf, float* __restrict__ pooled){
  __shared__ __align__(16) short sW[2][64][72];
  __shared__ __align__(16) short sA[2][64][72];
  __shared__ int sb[64];
  __shared__ unsigned long long runmask;
  const int tid  = threadIdx.x;
  const int lane = tid & 63, w = tid >> 6;
  const int jc   = lane & 15;
  const int g16  = w*4 + (lane >> 4);     // group id 0..15, owns rows 4*g16..+3
  const int mrow = 16*w + jc;
  const int koff = (lane >> 4) * 8;
  const int r0   = 16*w + (lane >> 4)*4;  // == 4*g16
  const int base = blockIdx.x * 64;

  float muv[4], invv[4], gav[4], bev[4], brv[4], g1v[4], w2v[4];
  #pragma unroll
  for (int nt = 0; nt < 4; ++nt){
    const int col = nt*16 + jc;
    muv[nt] = muinv[col];  invv[nt] = muinv[DIM+col];
    gav[nt] = gamma[col];  bev[nt]  = beta[col];
    brv[nt] = bres[col];   g1v[nt]  = gb1[col];
    w2v[nt] = gW2[col];
  }
  const float gb2v = gb2[0];

  // stage x into sA ; stage batch ids
  {
    const int row = tid >> 2;
    const int kq  = (tid & 3) * 16;
    const int node = base + row;
    #pragma unroll
    for (int cc = 0; cc < 4; ++cc){
      float4 v = make_float4(0.f,0.f,0.f,0.f);
      if (node < N_NODES) v = *(const float4*)&x[(size_t)node*DIM + kq + 4*cc];
      unsigned short h[4], l[4];
      split2(v.x,h[0],l[0]); split2(v.y,h[1],l[1]);
      split2(v.z,h[2],l[2]); split2(v.w,h[3],l[3]);
      uint2 ph, pl;
      ph.x = (unsigned)h[0] | ((unsigned)h[1]<<16);
      ph.y = (unsigned)h[2] | ((unsigned)h[3]<<16);
      pl.x = (unsigned)l[0] | ((unsigned)l[1]<<16);
      pl.y = (unsigned)l[2] | ((unsigned)l[3]<<16);
      *(uint2*)&sA[0][row][kq + 4*cc] = ph;
      *(uint2*)&sA[1][row][kq + 4*cc] = pl;
    }
  }
  if (tid < 64){
    int nn = base + tid;
    sb[tid] = batch[(nn < N_NODES) ? nn : (N_NODES-1)];
  }
  stage_w64(&sW[0][0][0], &sW[1][0][0], Wres, w, lane);
  __syncthreads();

  if (w == 0){
    bool fl = (lane > 0) && (sb[lane] != sb[lane-1]);
    unsigned long long mm = __ballot(fl);
    if (lane == 0) runmask = mm;
  }

  // GEMM1: acc = x @ Wres
  f32x4 acc[4] = {};
  #pragma unroll
  for (int kt2 = 0; kt2 < 2; ++kt2){
    const int ka = kt2*32 + koff;
    bf16x8 ah = *(const bf16x8*)&sA[0][mrow][ka];
    bf16x8 al = *(const bf16x8*)&sA[1][mrow][ka];
    #pragma unroll
    for (int nt = 0; nt < 4; ++nt){
      const int nr = nt*16 + jc;
      bf16x8 bh = *(const bf16x8*)&sW[0][nr][ka];
      bf16x8 bo = *(const bf16x8*)&sW[1][nr][ka];
      acc[nt] = __builtin_amdgcn_mfma_f32_16x16x32_bf16(ah, bh, acc[nt], 0,0,0);
      acc[nt] = __builtin_amdgcn_mfma_f32_16x16x32_bf16(al, bh, acc[nt], 0,0,0);
      acc[nt] = __builtin_amdgcn_mfma_f32_16x16x32_bf16(ah, bo, acc[nt], 0,0,0);
    }
  }

  // epilogue1: h2 = BN(hpre)+bres+acc ; keep in vk ; convert into sA
  float vk[4][4];
  #pragma unroll
  for (int nt = 0; nt < 4; ++nt){
    const int col = nt*16 + jc;
    #pragma unroll
    for (int r = 0; r < 4; ++r){
      const int node = base + r0 + r;
      float hp = 0.f;
      if (node < N_NODES) hp = hbuf[(size_t)node*DIM + col];
      float v = (hp - muv[nt])*invv[nt]*gav[nt] + bev[nt] + brv[nt] + acc[nt][r];
      vk[nt][r] = v;
      unsigned short hh, ll;
      split2(v, hh, ll);
      sA[0][r0 + r][col] = (short)hh;    // own-wave rows: no sync needed
      sA[1][r0 + r][col] = (short)ll;
    }
  }
  __syncthreads();
  stage_w64(&sW[0][0][0], &sW[1][0][0], gW1, w, lane);
  __syncthreads();

  // GEMM2: gp = h2 @ gW1
  f32x4 acc2[4] = {};
  #pragma unroll
  for (int kt2 = 0; kt2 < 2; ++kt2){
    const int ka = kt2*32 + koff;
    bf16x8 ah = *(const bf16x8*)&sA[0][mrow][ka];
    bf16x8 al = *(const bf16x8*)&sA[1][mrow][ka];
    #pragma unroll
    for (int nt = 0; nt < 4; ++nt){
      const int nr = nt*16 + jc;
      bf16x8 bh = *(const bf16x8*)&sW[0][nr][ka];
      bf16x8 bo = *(const bf16x8*)&sW[1][nr][ka];
      acc2[nt] = __builtin_amdgcn_mfma_f32_16x16x32_bf16(ah, bh, acc2[nt], 0,0,0);
      acc2[nt] = __builtin_amdgcn_mfma_f32_16x16x32_bf16(al, bh, acc2[nt], 0,0,0);
      acc2[nt] = __builtin_amdgcn_mfma_f32_16x16x32_bf16(ah, bo, acc2[nt], 0,0,0);
    }
  }

  // epilogue2: gate scalar per node -> e weights (all 16 lanes of group hold it)
  float p[4] = {0.f,0.f,0.f,0.f};
  #pragma unroll
  for (int nt = 0; nt < 4; ++nt){
    #pragma unroll
    for (int r = 0; r < 4; ++r)
      p[r] += fmaxf(acc2[nt][r] + g1v[nt], 0.f) * w2v[nt];
  }
  float ev[4];
  #pragma unroll
  for (int r = 0; r < 4; ++r){
    float t = p[r];
    t += __shfl_xor(t, 1, 64); t += __shfl_xor(t, 2, 64);
    t += __shfl_xor(t, 4, 64); t += __shfl_xor(t, 8, 64);
    const int node = base + r0 + r;
    ev[r] = (node < N_NODES) ? expf(t + gb2v) : 0.f;
  }

  // ---- fused pooling: run-aware block reduce -> global atomics ----
  float* sredp = (float*)&sA[0][0][0];   // sA free after GEMM2
  float* szl   = sredp + 16*64;
  __syncthreads();                       // GEMM2 sA reads complete
  const unsigned long long m = runmask;
  int rstart = 0;
  while (rstart < 64){
    const int bseg = sb[rstart];         // uniform
    unsigned long long rest = (rstart >= 63) ? 0ull : (m >> (rstart+1));
    const int rend = rest ? (rstart + 1 + __builtin_ctzll(rest)) : 64;
    float pacc[4] = {0.f,0.f,0.f,0.f};
    float zacc = 0.f;
    #pragma unroll
    for (int r = 0; r < 4; ++r){
      const int ln = 4*g16 + r;
      if (ln >= rstart && ln < rend){
        #pragma unroll
        for (int nt = 0; nt < 4; ++nt) pacc[nt] += ev[r]*vk[nt][r];
        zacc += ev[r];
      }
    }
    #pragma unroll
    for (int nt = 0; nt < 4; ++nt) sredp[g16*64 + nt*16 + jc] = pacc[nt];
    if ((lane & 15) == 0) szl[g16] = zacc;
    __syncthreads();
    if (tid < 64){
      float s = 0.f;
      #pragma unroll 4
      for (int g2 = 0; g2 < 16; ++g2) s += sredp[g2*64 + tid];
      atomicAdd(&pooled[bseg*DIM + tid], s);
    }
    if (tid == 64){
      float sz2 = 0.f;
      for (int g2 = 0; g2 < 16; ++g2) sz2 += szl[g2];
      atomicAdd(&zbuf[bseg], sz2);
    }
    __syncthreads();
    rstart = rend;
  }
}

// ---- K6: pooled/z -> relu(pooled@Wp1+bp1)@Wp2+bp2 ; one block per batch row ----
__global__ void k_head(const float* __restrict__ pooled, const float* __restrict__ zbuf,
                       const float* __restrict__ Wp1, const float* __restrict__ bp1,
                       const float* __restrict__ Wp2, const float* __restrict__ bp2,
                       float* __restrict__ out){
  __shared__ float ps[DIM];
  __shared__ float red[4];
  int b = blockIdx.x;
  int t = threadIdx.x; // 0..127
  if (t < DIM){
    float zz = fmaxf(zbuf[b], 1e-16f);
    ps[t] = pooled[b*DIM + t] / zz;
  }
  __syncthreads();
  float acc = bp1[t];
  #pragma unroll
  for (int d2=0; d2<DIM; d2++) acc = fmaf(ps[d2], Wp1[d2*HID + t], acc);
  acc = fmaxf(acc, 0.f);
  float o0 = acc * Wp2[t*NCLS+0];
  float o1 = acc * Wp2[t*NCLS+1];
  #pragma unroll
  for (int o=32;o>0;o>>=1){ o0 += __shfl_down(o0,o,64); o1 += __shfl_down(o1,o,64); }
  int w = t>>6;
  if ((t&63)==0){ red[w*2+0]=o0; red[w*2+1]=o1; }
  __syncthreads();
  if (t==0){
    out[b*NCLS+0] = red[0]+red[2]+bp2[0];
    out[b*NCLS+1] = red[1]+red[3]+bp2[1];
  }
}

extern "C" void kernel_launch(void* const* d_in, const int* in_sizes, int n_in,
                              void* d_out, int out_size, void* d_ws, size_t ws_size,
                              hipStream_t stream){
  const float* x     = (const float*)d_in[0];
  const int*   ei    = (const int*)d_in[1];
  const int*   batch = (const int*)d_in[2];
  const float* Wl    = (const float*)d_in[3];
  const float* bl    = (const float*)d_in[4];
  const float* Wr    = (const float*)d_in[5];
  const float* Wres  = (const float*)d_in[6];
  const float* bres  = (const float*)d_in[7];
  const float* gamma = (const float*)d_in[8];
  const float* beta  = (const float*)d_in[9];
  const float* gW1   = (const float*)d_in[10];
  const float* gb1   = (const float*)d_in[11];
  const float* gW2   = (const float*)d_in[12];
  const float* gb2   = (const float*)d_in[13];
  const float* Wp1   = (const float*)d_in[14];
  const float* bp1   = (const float*)d_in[15];
  const float* Wp2   = (const float*)d_in[16];
  const float* bp2   = (const float*)d_in[17];
  float* outp = (float*)d_out;

  // ---- workspace carve (zero-init region first, contiguous) ----
  int*   cnt   = (int*)d_ws;                            // N      (zeroed)
  float* zbuf  = (float*)(cnt + N_NODES);               // B      (zeroed)
  float* pooled= zbuf + BATCHES;                        // B*D    (zeroed)
  float* pstat = pooled + (size_t)BATCHES*DIM;          // NCHUNK1*128
  float* muinv = pstat + (size_t)NCHUNK1*128;           // 128
  float* meanb = muinv + 2*DIM;                         // N*D
  float* hbuf  = meanb + (size_t)N_NODES*DIM;           // N*D
  unsigned short* csr = (unsigned short*)(hbuf + (size_t)N_NODES*DIM); // N*MAXD u16

  const size_t zcount = (size_t)N_NODES + BATCHES + (size_t)BATCHES*DIM;
  hipMemsetAsync(d_ws, 0, zcount*sizeof(int), stream);

  k_scatter<<<NPART*NCHK_E, 256, 0, stream>>>(ei, cnt, csr);
  k_mean   <<<N_NODES/4, 256, 0, stream>>>(x, csr, cnt, meanb);
  k_lin1   <<<NCHUNK1, 256, 0, stream>>>(meanb, x, Wl, bl, Wr, hbuf, pstat);
  k_stats  <<<64, 256, 0, stream>>>(pstat, muinv);
  k_lin2   <<<NCHUNK1, 256, 0, stream>>>(x, hbuf, Wres, bres, gamma, beta, muinv,
                                         gW1, gb1, gW2, gb2, batch, zbuf, pooled);
  k_head   <<<BATCHES, HID, 0, stream>>>(pooled, zbuf, Wp1, bp1, Wp2, bp2, outp);
}